// Round 1
// baseline (3665.959 us; speedup 1.0000x reference)
//
#include <hip/hip_runtime.h>
#include <hip/hip_bf16.h>

#define EDGES 100000
#define TRIPS 500000
#define HC 128      // hidden
#define IC 64       // int_emb
#define NRC 6
#define SBF_K 42    // NS*NR
#define SBF_KP 44   // padded to mult of 4
#define T_K 294     // NS*NS*NR
#define T_KP 296    // padded to mult of 4

__device__ __forceinline__ float selu_f(float x) {
    const float scale = 1.0507009873554805f;
    const float alpha = 1.6732632423543772f;
    return x > 0.f ? scale * x : scale * alpha * expm1f(x);
}

// ---------------- combined small weights ----------------
// Wrbf_c = W_rbf1 @ W_rbf2  [6,128]
// Wsbf_c = W_sbf1 @ W_sbf2  [44,64] (rows 42,43 zero)
// Wt_c   = W_t1   @ W_t2    [296,64] (rows 294,295 zero)
__global__ void combos_kernel(const float* __restrict__ W_rbf1, const float* __restrict__ W_rbf2,
                              const float* __restrict__ W_sbf1, const float* __restrict__ W_sbf2,
                              const float* __restrict__ W_t1,   const float* __restrict__ W_t2,
                              float* __restrict__ Wrbf_c, float* __restrict__ Wsbf_c,
                              float* __restrict__ Wt_c) {
    int tid = blockIdx.x * blockDim.x + threadIdx.x;
    int stride = gridDim.x * blockDim.x;
    for (int idx = tid; idx < NRC * HC; idx += stride) {
        int r = idx / HC, h = idx % HC;
        float s = 0.f;
        for (int b = 0; b < 8; b++) s += W_rbf1[r * 8 + b] * W_rbf2[b * HC + h];
        Wrbf_c[idx] = s;
    }
    for (int idx = tid; idx < SBF_KP * IC; idx += stride) {
        int r = idx / IC, h = idx % IC;
        float s = 0.f;
        if (r < SBF_K)
            for (int b = 0; b < 8; b++) s += W_sbf1[r * 8 + b] * W_sbf2[b * IC + h];
        Wsbf_c[idx] = s;
    }
    for (int idx = tid; idx < T_KP * IC; idx += stride) {
        int r = idx / IC, h = idx % IC;
        float s = 0.f;
        if (r < T_K)
            for (int b = 0; b < 8; b++) s += W_t1[r * 8 + b] * W_t2[b * IC + h];
        Wt_c[idx] = s;
    }
}

// ---------------- edge front ----------------
// x_ji = selu(x1@W_ji+b_ji)                          -> xji_out [E,128]
// x_kj = selu(x1@W_kj+b_kj) * (rbf0@Wrbf_c)
// x_kj_down = selu(x_kj @ W_down)                    -> xkjd_out [E,64]
__global__ __launch_bounds__(256) void edge_front_kernel(
    const float* __restrict__ x1, const float* __restrict__ rbf0,
    const float* __restrict__ Wji, const float* __restrict__ bji,
    const float* __restrict__ Wkj, const float* __restrict__ bkj,
    const float* __restrict__ Wrbf_c, const float* __restrict__ Wdown,
    float* __restrict__ xji_out, float* __restrict__ xkjd_out) {
    __shared__ float xs[16][HC];
    __shared__ float xkj_s[16][HC];
    __shared__ float rbfs[16][8];
    const int e0 = blockIdx.x * 16;
    const int tid = threadIdx.x;

    {   // stage x1 tile (float4)
        const float4* src = (const float4*)(x1 + (size_t)e0 * HC);
        float4* dst = (float4*)&xs[0][0];
        for (int i = tid; i < 16 * HC / 4; i += 256) dst[i] = src[i];
        for (int i = tid; i < 16 * NRC; i += 256)
            rbfs[i / NRC][i % NRC] = rbf0[(size_t)e0 * NRC + i];
    }
    __syncthreads();

    const int h = tid & 127;
    const int g = tid >> 7;  // 0..1 ; edges g,g+2,...,g+14
    float aj[8], ak[8];
    {
        float bjv = bji[h], bkv = bkj[h];
#pragma unroll
        for (int j = 0; j < 8; j++) { aj[j] = bjv; ak[j] = bkv; }
    }
    for (int k4 = 0; k4 < HC / 4; k4++) {
        const int k = 4 * k4;
        float wj0 = Wji[(k + 0) * HC + h], wj1 = Wji[(k + 1) * HC + h];
        float wj2 = Wji[(k + 2) * HC + h], wj3 = Wji[(k + 3) * HC + h];
        float wk0 = Wkj[(k + 0) * HC + h], wk1 = Wkj[(k + 1) * HC + h];
        float wk2 = Wkj[(k + 2) * HC + h], wk3 = Wkj[(k + 3) * HC + h];
#pragma unroll
        for (int j = 0; j < 8; j++) {
            float4 xv = *(const float4*)&xs[g + 2 * j][k];
            aj[j] += xv.x * wj0 + xv.y * wj1 + xv.z * wj2 + xv.w * wj3;
            ak[j] += xv.x * wk0 + xv.y * wk1 + xv.z * wk2 + xv.w * wk3;
        }
    }
#pragma unroll
    for (int j = 0; j < 8; j++) {
        const int el = g + 2 * j;
        float rv = 0.f;
#pragma unroll
        for (int r = 0; r < NRC; r++) rv += rbfs[el][r] * Wrbf_c[r * HC + h];
        xji_out[(size_t)(e0 + el) * HC + h] = selu_f(aj[j]);
        xkj_s[el][h] = selu_f(ak[j]) * rv;
    }
    __syncthreads();

    // down-projection 128 -> 64
    const int i2 = tid & 63;
    const int g2 = tid >> 6;  // 0..3 ; edges g2, g2+4, g2+8, g2+12
    float ad[4] = {0.f, 0.f, 0.f, 0.f};
    for (int k4 = 0; k4 < HC / 4; k4++) {
        const int k = 4 * k4;
        float w0 = Wdown[(k + 0) * IC + i2], w1 = Wdown[(k + 1) * IC + i2];
        float w2 = Wdown[(k + 2) * IC + i2], w3 = Wdown[(k + 3) * IC + i2];
#pragma unroll
        for (int j = 0; j < 4; j++) {
            float4 xv = *(const float4*)&xkj_s[g2 + 4 * j][k];
            ad[j] += xv.x * w0 + xv.y * w1 + xv.z * w2 + xv.w * w3;
        }
    }
#pragma unroll
    for (int j = 0; j < 4; j++)
        xkjd_out[(size_t)(e0 + g2 + 4 * j) * IC + i2] = selu_f(ad[j]);
}

// ---------------- triplet ----------------
// y = xkjd[idx_kj] * (sbf@Wsbf_c) * (t@Wt_c) ; atomic scatter-add into seg[idx_ji]
__global__ __launch_bounds__(256) void triplet_kernel(
    const float* __restrict__ sbf, const float* __restrict__ tmat,
    const float* __restrict__ Wsbf_c, const float* __restrict__ Wt_c,
    const float* __restrict__ xkjd,
    const int* __restrict__ idx_kj, const int* __restrict__ idx_ji,
    float* __restrict__ seg) {
    __shared__ float sbf_s[32 * SBF_KP];
    __shared__ float t_s[32 * T_KP];
    const size_t t0 = (size_t)blockIdx.x * 32;
    const int tid = threadIdx.x;

    {   // stage rows (scalar coalesced; LDS rows padded)
        const float* src_t = tmat + t0 * T_K;
        for (int i = tid; i < 32 * T_K; i += 256)
            t_s[(i / T_K) * T_KP + (i % T_K)] = src_t[i];
        const float* src_s = sbf + t0 * SBF_K;
        for (int i = tid; i < 32 * SBF_K; i += 256)
            sbf_s[(i / SBF_K) * SBF_KP + (i % SBF_K)] = src_s[i];
        for (int r = tid; r < 32; r += 256) {
            t_s[r * T_KP + T_K] = 0.f;  t_s[r * T_KP + T_K + 1] = 0.f;
            sbf_s[r * SBF_KP + SBF_K] = 0.f;  sbf_s[r * SBF_KP + SBF_K + 1] = 0.f;
        }
    }
    __syncthreads();

    const int i = tid & 63;   // output channel
    const int g = tid >> 6;   // wave id: triplets g*8 .. g*8+7
    float acc_s[8], acc_t[8];
#pragma unroll
    for (int j = 0; j < 8; j++) { acc_s[j] = 0.f; acc_t[j] = 0.f; }

    for (int k4 = 0; k4 < SBF_KP / 4; k4++) {
        const int k = 4 * k4;
        float w0 = Wsbf_c[(k + 0) * IC + i], w1 = Wsbf_c[(k + 1) * IC + i];
        float w2 = Wsbf_c[(k + 2) * IC + i], w3 = Wsbf_c[(k + 3) * IC + i];
#pragma unroll
        for (int j = 0; j < 8; j++) {
            float4 xv = *(const float4*)&sbf_s[(g * 8 + j) * SBF_KP + k];
            acc_s[j] += xv.x * w0 + xv.y * w1 + xv.z * w2 + xv.w * w3;
        }
    }
    for (int k4 = 0; k4 < T_KP / 4; k4++) {
        const int k = 4 * k4;
        float w0 = Wt_c[(k + 0) * IC + i], w1 = Wt_c[(k + 1) * IC + i];
        float w2 = Wt_c[(k + 2) * IC + i], w3 = Wt_c[(k + 3) * IC + i];
#pragma unroll
        for (int j = 0; j < 8; j++) {
            float4 xv = *(const float4*)&t_s[(g * 8 + j) * T_KP + k];
            acc_t[j] += xv.x * w0 + xv.y * w1 + xv.z * w2 + xv.w * w3;
        }
    }
#pragma unroll
    for (int j = 0; j < 8; j++) {
        const size_t gt = t0 + g * 8 + j;
        const int ekj = idx_kj[gt];
        const int eji = idx_ji[gt];
        float y = xkjd[(size_t)ekj * IC + i] * acc_s[j] * acc_t[j];
        atomicAdd(&seg[(size_t)eji * IC + i], y);
    }
}

// ---------------- edge back ----------------
__global__ __launch_bounds__(256) void edge_back_kernel(
    const float* __restrict__ xji, const float* __restrict__ seg,
    const float* __restrict__ x1, const float* __restrict__ rbf0,
    const float* __restrict__ Wup,
    const float* __restrict__ resbW1, const float* __restrict__ resbb1,
    const float* __restrict__ resbW2, const float* __restrict__ resbb2,
    const float* __restrict__ Wlin, const float* __restrict__ blin,
    const float* __restrict__ resaW1, const float* __restrict__ resab1,
    const float* __restrict__ resaW2, const float* __restrict__ resab2,
    const float* __restrict__ Wrbf,
    float* __restrict__ e1_out, float* __restrict__ e2_out) {
    __shared__ float bufA[16][HC];
    __shared__ float bufB[16][HC];
    __shared__ float segs[16][IC];
    __shared__ float rbfs[16][8];
    const int e0 = blockIdx.x * 16;
    const int tid = threadIdx.x;
    const int h = tid & 127;
    const int g = tid >> 7;  // 0..1, edges g+2*j

    {
        const float4* src = (const float4*)(seg + (size_t)e0 * IC);
        float4* dst = (float4*)&segs[0][0];
        for (int i = tid; i < 16 * IC / 4; i += 256) dst[i] = src[i];
        for (int i = tid; i < 16 * NRC; i += 256)
            rbfs[i / NRC][i % NRC] = rbf0[(size_t)e0 * NRC + i];
    }
    __syncthreads();

    float acc[8];
    // --- up-projection + x_ji -> bufA
#pragma unroll
    for (int j = 0; j < 8; j++) acc[j] = 0.f;
    for (int k4 = 0; k4 < IC / 4; k4++) {
        const int k = 4 * k4;
        float w0 = Wup[(k + 0) * HC + h], w1 = Wup[(k + 1) * HC + h];
        float w2 = Wup[(k + 2) * HC + h], w3 = Wup[(k + 3) * HC + h];
#pragma unroll
        for (int j = 0; j < 8; j++) {
            float4 xv = *(const float4*)&segs[g + 2 * j][k];
            acc[j] += xv.x * w0 + xv.y * w1 + xv.z * w2 + xv.w * w3;
        }
    }
#pragma unroll
    for (int j = 0; j < 8; j++) {
        const int el = g + 2 * j;
        bufA[el][h] = selu_f(acc[j]) + xji[(size_t)(e0 + el) * HC + h];
    }
    __syncthreads();

    // --- res block (before skip), in place on bufA via bufB
    {
        float bv = resbb1[h];
#pragma unroll
        for (int j = 0; j < 8; j++) acc[j] = bv;
        for (int k4 = 0; k4 < HC / 4; k4++) {
            const int k = 4 * k4;
            float w0 = resbW1[(k + 0) * HC + h], w1 = resbW1[(k + 1) * HC + h];
            float w2 = resbW1[(k + 2) * HC + h], w3 = resbW1[(k + 3) * HC + h];
#pragma unroll
            for (int j = 0; j < 8; j++) {
                float4 xv = *(const float4*)&bufA[g + 2 * j][k];
                acc[j] += xv.x * w0 + xv.y * w1 + xv.z * w2 + xv.w * w3;
            }
        }
#pragma unroll
        for (int j = 0; j < 8; j++) bufB[g + 2 * j][h] = selu_f(acc[j]);
        __syncthreads();
        bv = resbb2[h];
#pragma unroll
        for (int j = 0; j < 8; j++) acc[j] = bv;
        for (int k4 = 0; k4 < HC / 4; k4++) {
            const int k = 4 * k4;
            float w0 = resbW2[(k + 0) * HC + h], w1 = resbW2[(k + 1) * HC + h];
            float w2 = resbW2[(k + 2) * HC + h], w3 = resbW2[(k + 3) * HC + h];
#pragma unroll
            for (int j = 0; j < 8; j++) {
                float4 xv = *(const float4*)&bufB[g + 2 * j][k];
                acc[j] += xv.x * w0 + xv.y * w1 + xv.z * w2 + xv.w * w3;
            }
        }
#pragma unroll
        for (int j = 0; j < 8; j++) { const int el = g + 2 * j; bufA[el][h] += selu_f(acc[j]); }
        __syncthreads();
    }

    // --- lin + x1 skip : bufB = selu(bufA@Wlin+blin) + x1
    {
        float bv = blin[h];
#pragma unroll
        for (int j = 0; j < 8; j++) acc[j] = bv;
        for (int k4 = 0; k4 < HC / 4; k4++) {
            const int k = 4 * k4;
            float w0 = Wlin[(k + 0) * HC + h], w1 = Wlin[(k + 1) * HC + h];
            float w2 = Wlin[(k + 2) * HC + h], w3 = Wlin[(k + 3) * HC + h];
#pragma unroll
            for (int j = 0; j < 8; j++) {
                float4 xv = *(const float4*)&bufA[g + 2 * j][k];
                acc[j] += xv.x * w0 + xv.y * w1 + xv.z * w2 + xv.w * w3;
            }
        }
#pragma unroll
        for (int j = 0; j < 8; j++) {
            const int el = g + 2 * j;
            bufB[el][h] = selu_f(acc[j]) + x1[(size_t)(e0 + el) * HC + h];
        }
        __syncthreads();
    }

    // --- 2 res blocks (after skip), in place on bufB via bufA
    for (int r = 0; r < 2; r++) {
        const float* W1 = resaW1 + (size_t)r * HC * HC;
        const float* B1 = resab1 + (size_t)r * HC;
        const float* W2 = resaW2 + (size_t)r * HC * HC;
        const float* B2 = resab2 + (size_t)r * HC;
        float bv = B1[h];
#pragma unroll
        for (int j = 0; j < 8; j++) acc[j] = bv;
        for (int k4 = 0; k4 < HC / 4; k4++) {
            const int k = 4 * k4;
            float w0 = W1[(k + 0) * HC + h], w1 = W1[(k + 1) * HC + h];
            float w2 = W1[(k + 2) * HC + h], w3 = W1[(k + 3) * HC + h];
#pragma unroll
            for (int j = 0; j < 8; j++) {
                float4 xv = *(const float4*)&bufB[g + 2 * j][k];
                acc[j] += xv.x * w0 + xv.y * w1 + xv.z * w2 + xv.w * w3;
            }
        }
#pragma unroll
        for (int j = 0; j < 8; j++) bufA[g + 2 * j][h] = selu_f(acc[j]);
        __syncthreads();
        bv = B2[h];
#pragma unroll
        for (int j = 0; j < 8; j++) acc[j] = bv;
        for (int k4 = 0; k4 < HC / 4; k4++) {
            const int k = 4 * k4;
            float w0 = W2[(k + 0) * HC + h], w1 = W2[(k + 1) * HC + h];
            float w2 = W2[(k + 2) * HC + h], w3 = W2[(k + 3) * HC + h];
#pragma unroll
            for (int j = 0; j < 8; j++) {
                float4 xv = *(const float4*)&bufA[g + 2 * j][k];
                acc[j] += xv.x * w0 + xv.y * w1 + xv.z * w2 + xv.w * w3;
            }
        }
#pragma unroll
        for (int j = 0; j < 8; j++) { const int el = g + 2 * j; bufB[el][h] += selu_f(acc[j]); }
        __syncthreads();
    }

    // --- outputs: e1, e2 = (rbf0@W_rbf)*e1
#pragma unroll
    for (int j = 0; j < 8; j++) {
        const int el = g + 2 * j;
        const size_t e = (size_t)(e0 + el);
        float v = bufB[el][h];
        float rv = 0.f;
#pragma unroll
        for (int r = 0; r < NRC; r++) rv += rbfs[el][r] * Wrbf[r * HC + h];
        e1_out[e * HC + h] = v;
        e2_out[e * HC + h] = rv * v;
    }
}

extern "C" void kernel_launch(void* const* d_in, const int* in_sizes, int n_in,
                              void* d_out, int out_size, void* d_ws, size_t ws_size,
                              hipStream_t stream) {
    const float* x1     = (const float*)d_in[0];
    const float* rbf0   = (const float*)d_in[1];
    const float* sbf    = (const float*)d_in[2];
    const float* tmat   = (const float*)d_in[3];
    // d_in[4] = q_r (unused by reference)
    const float* W_rbf1 = (const float*)d_in[5];
    const float* W_rbf2 = (const float*)d_in[6];
    const float* W_sbf1 = (const float*)d_in[7];
    const float* W_sbf2 = (const float*)d_in[8];
    const float* W_t1   = (const float*)d_in[9];
    const float* W_t2   = (const float*)d_in[10];
    const float* W_rbf  = (const float*)d_in[11];
    const float* W_kj   = (const float*)d_in[12];
    const float* b_kj   = (const float*)d_in[13];
    const float* W_ji   = (const float*)d_in[14];
    const float* b_ji   = (const float*)d_in[15];
    const float* W_down = (const float*)d_in[16];
    const float* W_up   = (const float*)d_in[17];
    const float* W_lin  = (const float*)d_in[18];
    const float* b_lin  = (const float*)d_in[19];
    const float* resbW1 = (const float*)d_in[20];
    const float* resbb1 = (const float*)d_in[21];
    const float* resbW2 = (const float*)d_in[22];
    const float* resbb2 = (const float*)d_in[23];
    const float* resaW1 = (const float*)d_in[24];
    const float* resab1 = (const float*)d_in[25];
    const float* resaW2 = (const float*)d_in[26];
    const float* resab2 = (const float*)d_in[27];
    const int* idx_kj   = (const int*)d_in[28];
    const int* idx_ji   = (const int*)d_in[29];

    float* ws = (float*)d_ws;
    float* Wrbf_c = ws;                         // 6*128   = 768
    float* Wsbf_c = ws + 768;                   // 44*64   = 2816
    float* Wt_c   = ws + 768 + 2816;            // 296*64  = 18944
    float* xkjd   = ws + 768 + 2816 + 18944;    // E*64
    float* seg    = xkjd + (size_t)EDGES * IC;  // E*64

    float* e1_out = (float*)d_out;
    float* e2_out = e1_out + (size_t)EDGES * HC;
    float* xji    = e1_out;  // park x_ji in the e1 output region

    hipMemsetAsync(seg, 0, (size_t)EDGES * IC * sizeof(float), stream);
    combos_kernel<<<64, 256, 0, stream>>>(W_rbf1, W_rbf2, W_sbf1, W_sbf2, W_t1, W_t2,
                                          Wrbf_c, Wsbf_c, Wt_c);
    edge_front_kernel<<<EDGES / 16, 256, 0, stream>>>(x1, rbf0, W_ji, b_ji, W_kj, b_kj,
                                                      Wrbf_c, W_down, xji, xkjd);
    triplet_kernel<<<TRIPS / 32, 256, 0, stream>>>(sbf, tmat, Wsbf_c, Wt_c, xkjd,
                                                   idx_kj, idx_ji, seg);
    edge_back_kernel<<<EDGES / 16, 256, 0, stream>>>(xji, seg, x1, rbf0, W_up,
                                                     resbW1, resbb1, resbW2, resbb2,
                                                     W_lin, b_lin,
                                                     resaW1, resab1, resaW2, resab2,
                                                     W_rbf, e1_out, e2_out);
}

// Round 2
// 1915.908 us; speedup vs baseline: 1.9134x; 1.9134x over previous
//
#include <hip/hip_runtime.h>
#include <hip/hip_bf16.h>

#define EDGES 100000
#define TRIPS 500000
#define HC 128      // hidden
#define IC 64       // int_emb
#define NRC 6
#define SBF_K 42    // NS*NR
#define T_K 294     // NS*NS*NR

#define TSLAB 32    // triplet rows per staging slab
#define T_LW 328    // LDS row stride (bf16) for t   (328*2B=656B = 164 words ≡ 4 mod 32)
#define S_LW 72     // LDS row stride (bf16) for sbf (144B = 36 words ≡ 4 mod 32)
#define T_KSTEPS 10 // ceil(294/32)
#define S_KSTEPS 2  // ceil(42/32)

typedef __attribute__((ext_vector_type(8))) short bf16x8;
typedef __attribute__((ext_vector_type(4))) float f32x4;

__device__ __forceinline__ float selu_f(float x) {
    const float scale = 1.0507009873554805f;
    const float alpha = 1.6732632423543772f;
    return x > 0.f ? scale * x : scale * alpha * expm1f(x);
}

__device__ __forceinline__ unsigned short f2bf(float f) {
    unsigned int u = __float_as_uint(f);
    u += 0x7fffu + ((u >> 16) & 1u);   // round-nearest-even (inputs are finite)
    return (unsigned short)(u >> 16);
}

// ---------------- combined small weights + bf16 MFMA B-fragment packs ----------------
// Wrbf_c  = W_rbf1 @ W_rbf2  [6,128]  (f32, for edge_front)
// Wt_pack = bf16 B-fragments of (W_t1@W_t2)   [T_KSTEPS][4 ntiles][64 lanes][8]
// Ws_pack = bf16 B-fragments of (W_sbf1@W_sbf2) [S_KSTEPS][4][64][8]
__global__ void combos_kernel(const float* __restrict__ W_rbf1, const float* __restrict__ W_rbf2,
                              const float* __restrict__ W_sbf1, const float* __restrict__ W_sbf2,
                              const float* __restrict__ W_t1,   const float* __restrict__ W_t2,
                              float* __restrict__ Wrbf_c,
                              unsigned short* __restrict__ Wt_pack,
                              unsigned short* __restrict__ Ws_pack) {
    int tid = blockIdx.x * blockDim.x + threadIdx.x;
    int stride = gridDim.x * blockDim.x;
    for (int idx = tid; idx < NRC * HC; idx += stride) {
        int r = idx / HC, h = idx % HC;
        float s = 0.f;
        for (int b = 0; b < 8; b++) s += W_rbf1[r * 8 + b] * W_rbf2[b * HC + h];
        Wrbf_c[idx] = s;
    }
    for (int idx = tid; idx < T_KSTEPS * 4 * 64 * 8; idx += stride) {
        int j = idx & 7, l = (idx >> 3) & 63, n = (idx >> 9) & 3, s = idx >> 11;
        int k = s * 32 + (l >> 4) * 8 + j;
        int c = n * 16 + (l & 15);
        float v = 0.f;
        if (k < T_K)
            for (int b = 0; b < 8; b++) v += W_t1[k * 8 + b] * W_t2[b * IC + c];
        Wt_pack[idx] = f2bf(v);
    }
    for (int idx = tid; idx < S_KSTEPS * 4 * 64 * 8; idx += stride) {
        int j = idx & 7, l = (idx >> 3) & 63, n = (idx >> 9) & 3, s = idx >> 11;
        int k = s * 32 + (l >> 4) * 8 + j;
        int c = n * 16 + (l & 15);
        float v = 0.f;
        if (k < SBF_K)
            for (int b = 0; b < 8; b++) v += W_sbf1[k * 8 + b] * W_sbf2[b * IC + c];
        Ws_pack[idx] = f2bf(v);
    }
}

// ---------------- edge front ----------------
__global__ __launch_bounds__(256) void edge_front_kernel(
    const float* __restrict__ x1, const float* __restrict__ rbf0,
    const float* __restrict__ Wji, const float* __restrict__ bji,
    const float* __restrict__ Wkj, const float* __restrict__ bkj,
    const float* __restrict__ Wrbf_c, const float* __restrict__ Wdown,
    float* __restrict__ xji_out, float* __restrict__ xkjd_out) {
    __shared__ float xs[16][HC];
    __shared__ float xkj_s[16][HC];
    __shared__ float rbfs[16][8];
    const int e0 = blockIdx.x * 16;
    const int tid = threadIdx.x;

    {
        const float4* src = (const float4*)(x1 + (size_t)e0 * HC);
        float4* dst = (float4*)&xs[0][0];
        for (int i = tid; i < 16 * HC / 4; i += 256) dst[i] = src[i];
        for (int i = tid; i < 16 * NRC; i += 256)
            rbfs[i / NRC][i % NRC] = rbf0[(size_t)e0 * NRC + i];
    }
    __syncthreads();

    const int h = tid & 127;
    const int g = tid >> 7;
    float aj[8], ak[8];
    {
        float bjv = bji[h], bkv = bkj[h];
#pragma unroll
        for (int j = 0; j < 8; j++) { aj[j] = bjv; ak[j] = bkv; }
    }
    for (int k4 = 0; k4 < HC / 4; k4++) {
        const int k = 4 * k4;
        float wj0 = Wji[(k + 0) * HC + h], wj1 = Wji[(k + 1) * HC + h];
        float wj2 = Wji[(k + 2) * HC + h], wj3 = Wji[(k + 3) * HC + h];
        float wk0 = Wkj[(k + 0) * HC + h], wk1 = Wkj[(k + 1) * HC + h];
        float wk2 = Wkj[(k + 2) * HC + h], wk3 = Wkj[(k + 3) * HC + h];
#pragma unroll
        for (int j = 0; j < 8; j++) {
            float4 xv = *(const float4*)&xs[g + 2 * j][k];
            aj[j] += xv.x * wj0 + xv.y * wj1 + xv.z * wj2 + xv.w * wj3;
            ak[j] += xv.x * wk0 + xv.y * wk1 + xv.z * wk2 + xv.w * wk3;
        }
    }
#pragma unroll
    for (int j = 0; j < 8; j++) {
        const int el = g + 2 * j;
        float rv = 0.f;
#pragma unroll
        for (int r = 0; r < NRC; r++) rv += rbfs[el][r] * Wrbf_c[r * HC + h];
        xji_out[(size_t)(e0 + el) * HC + h] = selu_f(aj[j]);
        xkj_s[el][h] = selu_f(ak[j]) * rv;
    }
    __syncthreads();

    const int i2 = tid & 63;
    const int g2 = tid >> 6;
    float ad[4] = {0.f, 0.f, 0.f, 0.f};
    for (int k4 = 0; k4 < HC / 4; k4++) {
        const int k = 4 * k4;
        float w0 = Wdown[(k + 0) * IC + i2], w1 = Wdown[(k + 1) * IC + i2];
        float w2 = Wdown[(k + 2) * IC + i2], w3 = Wdown[(k + 3) * IC + i2];
#pragma unroll
        for (int j = 0; j < 4; j++) {
            float4 xv = *(const float4*)&xkj_s[g2 + 4 * j][k];
            ad[j] += xv.x * w0 + xv.y * w1 + xv.z * w2 + xv.w * w3;
        }
    }
#pragma unroll
    for (int j = 0; j < 4; j++)
        xkjd_out[(size_t)(e0 + g2 + 4 * j) * IC + i2] = selu_f(ad[j]);
}

// ---------------- triplet (bf16 MFMA) ----------------
// y[m][c] = xkjd[idx_kj[m]][c] * (sbf@Wsbf_c)[m][c] * (t@Wt_c)[m][c]
// atomic scatter-add into seg[idx_ji[m]][c]
__global__ __launch_bounds__(256) void triplet_mfma_kernel(
    const float* __restrict__ sbf, const float* __restrict__ tmat,
    const unsigned short* __restrict__ Wt_pack,
    const unsigned short* __restrict__ Ws_pack,
    const float* __restrict__ xkjd,
    const int* __restrict__ idx_kj, const int* __restrict__ idx_ji,
    float* __restrict__ seg, int nslab) {
    __shared__ __align__(16) unsigned short t_lds[TSLAB][T_LW];
    __shared__ __align__(16) unsigned short s_lds[TSLAB][S_LW];
    __shared__ int kj_s[TSLAB], ji_s[TSLAB];
    const int tid = threadIdx.x;
    const int lane = tid & 63;
    const int w = tid >> 6;   // wave id = N-tile (16 channels)

    // B fragments: resident for the whole kernel
    bf16x8 bt[T_KSTEPS], bs[S_KSTEPS];
#pragma unroll
    for (int s = 0; s < T_KSTEPS; s++)
        bt[s] = *(const bf16x8*)(Wt_pack + (size_t)((s * 4 + w) * 64 + lane) * 8);
#pragma unroll
    for (int s = 0; s < S_KSTEPS; s++)
        bs[s] = *(const bf16x8*)(Ws_pack + (size_t)((s * 4 + w) * 64 + lane) * 8);

    // zero the K-pad columns once (re-used across all slabs)
    for (int i = tid; i < TSLAB * (T_KSTEPS * 32 - T_K); i += 256) {
        int r = i / (T_KSTEPS * 32 - T_K), c = T_K + i % (T_KSTEPS * 32 - T_K);
        t_lds[r][c] = 0;
    }
    for (int i = tid; i < TSLAB * (S_KSTEPS * 32 - SBF_K); i += 256) {
        int r = i / (S_KSTEPS * 32 - SBF_K), c = SBF_K + i % (S_KSTEPS * 32 - SBF_K);
        s_lds[r][c] = 0;
    }

    for (int slab = blockIdx.x; slab < nslab; slab += gridDim.x) {
        const size_t t0 = (size_t)slab * TSLAB;
        // ---- stage t slab (contiguous f32 -> bf16 LDS, padded rows)
        {
            const float4* st = (const float4*)(tmat + t0 * T_K);
            for (int i = tid; i < TSLAB * T_K / 4; i += 256) {
                float4 v = st[i];
                int e = 4 * i;
                int r = e / T_K, c = e - r * T_K;
                float vv[4] = {v.x, v.y, v.z, v.w};
#pragma unroll
                for (int q = 0; q < 4; q++) {
                    t_lds[r][c] = f2bf(vv[q]);
                    if (++c == T_K) { c = 0; ++r; }
                }
            }
            const float4* ss = (const float4*)(sbf + t0 * SBF_K);
            for (int i = tid; i < TSLAB * SBF_K / 4; i += 256) {
                float4 v = ss[i];
                int e = 4 * i;
                int r = e / SBF_K, c = e - r * SBF_K;
                float vv[4] = {v.x, v.y, v.z, v.w};
#pragma unroll
                for (int q = 0; q < 4; q++) {
                    s_lds[r][c] = f2bf(vv[q]);
                    if (++c == SBF_K) { c = 0; ++r; }
                }
            }
            if (tid < TSLAB) {
                kj_s[tid] = idx_kj[t0 + tid];
                ji_s[tid] = idx_ji[t0 + tid];
            }
        }
        __syncthreads();

        // ---- MFMA: 2 M-tiles x (10 t-ksteps + 2 sbf-ksteps)
        const int arow0 = lane & 15;
        const int koff = (lane >> 4) * 8;
        f32x4 acc_t[2], acc_s[2];
#pragma unroll
        for (int mt = 0; mt < 2; mt++) {
            acc_t[mt] = (f32x4){0.f, 0.f, 0.f, 0.f};
            acc_s[mt] = (f32x4){0.f, 0.f, 0.f, 0.f};
        }
#pragma unroll
        for (int mt = 0; mt < 2; mt++) {
            const int row = mt * 16 + arow0;
#pragma unroll
            for (int s = 0; s < T_KSTEPS; s++) {
                bf16x8 a = *(const bf16x8*)&t_lds[row][s * 32 + koff];
                acc_t[mt] = __builtin_amdgcn_mfma_f32_16x16x32_bf16(a, bt[s], acc_t[mt], 0, 0, 0);
            }
#pragma unroll
            for (int s = 0; s < S_KSTEPS; s++) {
                bf16x8 a = *(const bf16x8*)&s_lds[row][s * 32 + koff];
                acc_s[mt] = __builtin_amdgcn_mfma_f32_16x16x32_bf16(a, bs[s], acc_s[mt], 0, 0, 0);
            }
        }

        // ---- epilogue: gather * product, atomic scatter
        const int ch = w * 16 + (lane & 15);
#pragma unroll
        for (int mt = 0; mt < 2; mt++) {
#pragma unroll
            for (int r = 0; r < 4; r++) {
                int ml = mt * 16 + (lane >> 4) * 4 + r;
                int ekj = kj_s[ml];
                int eji = ji_s[ml];
                float y = xkjd[(size_t)ekj * IC + ch] * acc_s[mt][r] * acc_t[mt][r];
                atomicAdd(&seg[(size_t)eji * IC + ch], y);
            }
        }
        __syncthreads();
    }
}

// ---------------- edge back ----------------
__global__ __launch_bounds__(256) void edge_back_kernel(
    const float* __restrict__ xji, const float* __restrict__ seg,
    const float* __restrict__ x1, const float* __restrict__ rbf0,
    const float* __restrict__ Wup,
    const float* __restrict__ resbW1, const float* __restrict__ resbb1,
    const float* __restrict__ resbW2, const float* __restrict__ resbb2,
    const float* __restrict__ Wlin, const float* __restrict__ blin,
    const float* __restrict__ resaW1, const float* __restrict__ resab1,
    const float* __restrict__ resaW2, const float* __restrict__ resab2,
    const float* __restrict__ Wrbf,
    float* __restrict__ e1_out, float* __restrict__ e2_out) {
    __shared__ float bufA[16][HC];
    __shared__ float bufB[16][HC];
    __shared__ float segs[16][IC];
    __shared__ float rbfs[16][8];
    const int e0 = blockIdx.x * 16;
    const int tid = threadIdx.x;
    const int h = tid & 127;
    const int g = tid >> 7;

    {
        const float4* src = (const float4*)(seg + (size_t)e0 * IC);
        float4* dst = (float4*)&segs[0][0];
        for (int i = tid; i < 16 * IC / 4; i += 256) dst[i] = src[i];
        for (int i = tid; i < 16 * NRC; i += 256)
            rbfs[i / NRC][i % NRC] = rbf0[(size_t)e0 * NRC + i];
    }
    __syncthreads();

    float acc[8];
#pragma unroll
    for (int j = 0; j < 8; j++) acc[j] = 0.f;
    for (int k4 = 0; k4 < IC / 4; k4++) {
        const int k = 4 * k4;
        float w0 = Wup[(k + 0) * HC + h], w1 = Wup[(k + 1) * HC + h];
        float w2 = Wup[(k + 2) * HC + h], w3 = Wup[(k + 3) * HC + h];
#pragma unroll
        for (int j = 0; j < 8; j++) {
            float4 xv = *(const float4*)&segs[g + 2 * j][k];
            acc[j] += xv.x * w0 + xv.y * w1 + xv.z * w2 + xv.w * w3;
        }
    }
#pragma unroll
    for (int j = 0; j < 8; j++) {
        const int el = g + 2 * j;
        bufA[el][h] = selu_f(acc[j]) + xji[(size_t)(e0 + el) * HC + h];
    }
    __syncthreads();

    {
        float bv = resbb1[h];
#pragma unroll
        for (int j = 0; j < 8; j++) acc[j] = bv;
        for (int k4 = 0; k4 < HC / 4; k4++) {
            const int k = 4 * k4;
            float w0 = resbW1[(k + 0) * HC + h], w1 = resbW1[(k + 1) * HC + h];
            float w2 = resbW1[(k + 2) * HC + h], w3 = resbW1[(k + 3) * HC + h];
#pragma unroll
            for (int j = 0; j < 8; j++) {
                float4 xv = *(const float4*)&bufA[g + 2 * j][k];
                acc[j] += xv.x * w0 + xv.y * w1 + xv.z * w2 + xv.w * w3;
            }
        }
#pragma unroll
        for (int j = 0; j < 8; j++) bufB[g + 2 * j][h] = selu_f(acc[j]);
        __syncthreads();
        bv = resbb2[h];
#pragma unroll
        for (int j = 0; j < 8; j++) acc[j] = bv;
        for (int k4 = 0; k4 < HC / 4; k4++) {
            const int k = 4 * k4;
            float w0 = resbW2[(k + 0) * HC + h], w1 = resbW2[(k + 1) * HC + h];
            float w2 = resbW2[(k + 2) * HC + h], w3 = resbW2[(k + 3) * HC + h];
#pragma unroll
            for (int j = 0; j < 8; j++) {
                float4 xv = *(const float4*)&bufB[g + 2 * j][k];
                acc[j] += xv.x * w0 + xv.y * w1 + xv.z * w2 + xv.w * w3;
            }
        }
#pragma unroll
        for (int j = 0; j < 8; j++) { const int el = g + 2 * j; bufA[el][h] += selu_f(acc[j]); }
        __syncthreads();
    }

    {
        float bv = blin[h];
#pragma unroll
        for (int j = 0; j < 8; j++) acc[j] = bv;
        for (int k4 = 0; k4 < HC / 4; k4++) {
            const int k = 4 * k4;
            float w0 = Wlin[(k + 0) * HC + h], w1 = Wlin[(k + 1) * HC + h];
            float w2 = Wlin[(k + 2) * HC + h], w3 = Wlin[(k + 3) * HC + h];
#pragma unroll
            for (int j = 0; j < 8; j++) {
                float4 xv = *(const float4*)&bufA[g + 2 * j][k];
                acc[j] += xv.x * w0 + xv.y * w1 + xv.z * w2 + xv.w * w3;
            }
        }
#pragma unroll
        for (int j = 0; j < 8; j++) {
            const int el = g + 2 * j;
            bufB[el][h] = selu_f(acc[j]) + x1[(size_t)(e0 + el) * HC + h];
        }
        __syncthreads();
    }

    for (int r = 0; r < 2; r++) {
        const float* W1 = resaW1 + (size_t)r * HC * HC;
        const float* B1 = resab1 + (size_t)r * HC;
        const float* W2 = resaW2 + (size_t)r * HC * HC;
        const float* B2 = resab2 + (size_t)r * HC;
        float bv = B1[h];
#pragma unroll
        for (int j = 0; j < 8; j++) acc[j] = bv;
        for (int k4 = 0; k4 < HC / 4; k4++) {
            const int k = 4 * k4;
            float w0 = W1[(k + 0) * HC + h], w1 = W1[(k + 1) * HC + h];
            float w2 = W1[(k + 2) * HC + h], w3 = W1[(k + 3) * HC + h];
#pragma unroll
            for (int j = 0; j < 8; j++) {
                float4 xv = *(const float4*)&bufB[g + 2 * j][k];
                acc[j] += xv.x * w0 + xv.y * w1 + xv.z * w2 + xv.w * w3;
            }
        }
#pragma unroll
        for (int j = 0; j < 8; j++) bufA[g + 2 * j][h] = selu_f(acc[j]);
        __syncthreads();
        bv = B2[h];
#pragma unroll
        for (int j = 0; j < 8; j++) acc[j] = bv;
        for (int k4 = 0; k4 < HC / 4; k4++) {
            const int k = 4 * k4;
            float w0 = W2[(k + 0) * HC + h], w1 = W2[(k + 1) * HC + h];
            float w2 = W2[(k + 2) * HC + h], w3 = W2[(k + 3) * HC + h];
#pragma unroll
            for (int j = 0; j < 8; j++) {
                float4 xv = *(const float4*)&bufA[g + 2 * j][k];
                acc[j] += xv.x * w0 + xv.y * w1 + xv.z * w2 + xv.w * w3;
            }
        }
#pragma unroll
        for (int j = 0; j < 8; j++) { const int el = g + 2 * j; bufB[el][h] += selu_f(acc[j]); }
        __syncthreads();
    }

#pragma unroll
    for (int j = 0; j < 8; j++) {
        const int el = g + 2 * j;
        const size_t e = (size_t)(e0 + el);
        float v = bufB[el][h];
        float rv = 0.f;
#pragma unroll
        for (int r = 0; r < NRC; r++) rv += rbfs[el][r] * Wrbf[r * HC + h];
        e1_out[e * HC + h] = v;
        e2_out[e * HC + h] = rv * v;
    }
}

extern "C" void kernel_launch(void* const* d_in, const int* in_sizes, int n_in,
                              void* d_out, int out_size, void* d_ws, size_t ws_size,
                              hipStream_t stream) {
    const float* x1     = (const float*)d_in[0];
    const float* rbf0   = (const float*)d_in[1];
    const float* sbf    = (const float*)d_in[2];
    const float* tmat   = (const float*)d_in[3];
    const float* W_rbf1 = (const float*)d_in[5];
    const float* W_rbf2 = (const float*)d_in[6];
    const float* W_sbf1 = (const float*)d_in[7];
    const float* W_sbf2 = (const float*)d_in[8];
    const float* W_t1   = (const float*)d_in[9];
    const float* W_t2   = (const float*)d_in[10];
    const float* W_rbf  = (const float*)d_in[11];
    const float* W_kj   = (const float*)d_in[12];
    const float* b_kj   = (const float*)d_in[13];
    const float* W_ji   = (const float*)d_in[14];
    const float* b_ji   = (const float*)d_in[15];
    const float* W_down = (const float*)d_in[16];
    const float* W_up   = (const float*)d_in[17];
    const float* W_lin  = (const float*)d_in[18];
    const float* b_lin  = (const float*)d_in[19];
    const float* resbW1 = (const float*)d_in[20];
    const float* resbb1 = (const float*)d_in[21];
    const float* resbW2 = (const float*)d_in[22];
    const float* resbb2 = (const float*)d_in[23];
    const float* resaW1 = (const float*)d_in[24];
    const float* resab1 = (const float*)d_in[25];
    const float* resaW2 = (const float*)d_in[26];
    const float* resab2 = (const float*)d_in[27];
    const int* idx_kj   = (const int*)d_in[28];
    const int* idx_ji   = (const int*)d_in[29];

    float* ws = (float*)d_ws;
    float* Wrbf_c = ws;                                  // 768 f32
    unsigned short* Wt_pack = (unsigned short*)(ws + 768);   // 10*4*64*8 = 20480 bf16
    unsigned short* Ws_pack = Wt_pack + T_KSTEPS * 4 * 64 * 8; // 4096 bf16
    float* xkjd = ws + 768 + (T_KSTEPS + S_KSTEPS) * 4 * 64 * 8 / 2;  // = ws + 13056
    float* seg  = xkjd + (size_t)EDGES * IC;

    float* e1_out = (float*)d_out;
    float* e2_out = e1_out + (size_t)EDGES * HC;
    float* xji    = e1_out;  // park x_ji in the e1 output region

    hipMemsetAsync(seg, 0, (size_t)EDGES * IC * sizeof(float), stream);
    combos_kernel<<<64, 256, 0, stream>>>(W_rbf1, W_rbf2, W_sbf1, W_sbf2, W_t1, W_t2,
                                          Wrbf_c, Wt_pack, Ws_pack);
    edge_front_kernel<<<EDGES / 16, 256, 0, stream>>>(x1, rbf0, W_ji, b_ji, W_kj, b_kj,
                                                      Wrbf_c, W_down, xji, xkjd);
    triplet_mfma_kernel<<<2048, 256, 0, stream>>>(sbf, tmat, Wt_pack, Ws_pack, xkjd,
                                                  idx_kj, idx_ji, seg, TRIPS / TSLAB);
    edge_back_kernel<<<EDGES / 16, 256, 0, stream>>>(xji, seg, x1, rbf0, W_up,
                                                     resbW1, resbb1, resbW2, resbb2,
                                                     W_lin, b_lin,
                                                     resaW1, resab1, resaW2, resab2,
                                                     W_rbf, e1_out, e2_out);
}

// Round 3
// 459.534 us; speedup vs baseline: 7.9776x; 4.1692x over previous
//
#include <hip/hip_runtime.h>
#include <hip/hip_bf16.h>

#define EDGES 100000
#define TRIPS 500000
#define HC 128
#define IC 64
#define NRC 6
#define SBF_K 42
#define T_K 294

#define TSLAB 32
#define T_LW 328
#define S_LW 72
#define T_KSTEPS 10
#define S_KSTEPS 2

typedef __attribute__((ext_vector_type(8))) short bf16x8;
typedef __attribute__((ext_vector_type(4))) float f32x4;

__device__ __forceinline__ float selu_f(float x) {
    const float scale = 1.0507009873554805f;
    const float alpha = 1.6732632423543772f;
    return x > 0.f ? scale * x : scale * alpha * expm1f(x);
}

__device__ __forceinline__ unsigned short f2bf(float f) {
    unsigned int u = __float_as_uint(f);
    u += 0x7fffu + ((u >> 16) & 1u);
    return (unsigned short)(u >> 16);
}

// swizzled bf16 activation tile [32 rows][128 cols], row stride 256B
__device__ __forceinline__ bf16x8 ldsA(const unsigned short* act, int row, int kbf) {
    int byte = row * 256 + kbf * 2;
    byte ^= (row & 7) << 4;
    return *(const bf16x8*)((const char*)act + byte);
}
__device__ __forceinline__ void ldsW(unsigned short* act, int row, int col, unsigned short v) {
    int byte = row * 256 + col * 2;
    byte ^= (row & 7) << 4;
    *(unsigned short*)((char*)act + byte) = v;
}
__device__ __forceinline__ void ldsW8B(unsigned short* act, int row, int col4, // col4 = col/4
                                       float a, float b, float c, float d) {
    unsigned long long v = (unsigned long long)(f2bf(a) | ((unsigned)f2bf(b) << 16)) |
                           ((unsigned long long)(f2bf(c) | ((unsigned)f2bf(d) << 16)) << 32);
    int byte = row * 256 + col4 * 8;
    byte ^= (row & 7) << 4;
    *(unsigned long long*)((char*)act + byte) = v;
}

// 2 M-tiles x KS k-steps GEMM on the act tile
template <int KS>
__device__ __forceinline__ void mm2(const unsigned short* act, const bf16x8* B,
                                    int lane, f32x4* acc) {
    const int ar = lane & 15;
    const int koff = (lane >> 4) * 8;
#pragma unroll
    for (int mt = 0; mt < 2; mt++) {
        f32x4 c = {0.f, 0.f, 0.f, 0.f};
#pragma unroll
        for (int ks = 0; ks < KS; ks++) {
            bf16x8 a = ldsA(act, mt * 16 + ar, ks * 32 + koff);
            c = __builtin_amdgcn_mfma_f32_16x16x32_bf16(a, B[ks], c, 0, 0, 0);
        }
        acc[mt] = c;
    }
}

// ---------------- combos: combined weights + B-fragment packs ----------------
__device__ __forceinline__ void pack_w(const float* __restrict__ W, int K, int N,
                                       unsigned short* __restrict__ dst, int tid, int stride) {
    const int nt = N >> 4;
    const int total = (K >> 5) * nt * 512;
    for (int idx = tid; idx < total; idx += stride) {
        int j = idx & 7, l = (idx >> 3) & 63;
        int t = idx >> 9;
        int n = t % nt, ks = t / nt;
        int k = ks * 32 + ((l >> 4) << 3) + j;
        int c = n * 16 + (l & 15);
        dst[idx] = f2bf(W[k * N + c]);
    }
}

__global__ void combos_kernel(const float* __restrict__ W_rbf1, const float* __restrict__ W_rbf2,
                              const float* __restrict__ W_sbf1, const float* __restrict__ W_sbf2,
                              const float* __restrict__ W_t1,   const float* __restrict__ W_t2,
                              const float* __restrict__ W_ji,   const float* __restrict__ W_kj,
                              const float* __restrict__ W_down, const float* __restrict__ W_up,
                              const float* __restrict__ resbW1, const float* __restrict__ resbW2,
                              const float* __restrict__ W_lin,
                              const float* __restrict__ resaW1, const float* __restrict__ resaW2,
                              float* __restrict__ Wrbf_c,
                              unsigned short* __restrict__ Wt_pack,
                              unsigned short* __restrict__ Ws_pack,
                              unsigned short* __restrict__ Pji, unsigned short* __restrict__ Pkj,
                              unsigned short* __restrict__ Pdown, unsigned short* __restrict__ Pup,
                              unsigned short* __restrict__ Prb1, unsigned short* __restrict__ Prb2,
                              unsigned short* __restrict__ Plin,
                              unsigned short* __restrict__ Pra10, unsigned short* __restrict__ Pra20,
                              unsigned short* __restrict__ Pra11, unsigned short* __restrict__ Pra21) {
    int tid = blockIdx.x * blockDim.x + threadIdx.x;
    int stride = gridDim.x * blockDim.x;
    for (int idx = tid; idx < NRC * HC; idx += stride) {
        int r = idx / HC, h = idx % HC;
        float s = 0.f;
        for (int b = 0; b < 8; b++) s += W_rbf1[r * 8 + b] * W_rbf2[b * HC + h];
        Wrbf_c[idx] = s;
    }
    for (int idx = tid; idx < T_KSTEPS * 4 * 64 * 8; idx += stride) {
        int j = idx & 7, l = (idx >> 3) & 63, n = (idx >> 9) & 3, s = idx >> 11;
        int k = s * 32 + (l >> 4) * 8 + j;
        int c = n * 16 + (l & 15);
        float v = 0.f;
        if (k < T_K)
            for (int b = 0; b < 8; b++) v += W_t1[k * 8 + b] * W_t2[b * IC + c];
        Wt_pack[idx] = f2bf(v);
    }
    for (int idx = tid; idx < S_KSTEPS * 4 * 64 * 8; idx += stride) {
        int j = idx & 7, l = (idx >> 3) & 63, n = (idx >> 9) & 3, s = idx >> 11;
        int k = s * 32 + (l >> 4) * 8 + j;
        int c = n * 16 + (l & 15);
        float v = 0.f;
        if (k < SBF_K)
            for (int b = 0; b < 8; b++) v += W_sbf1[k * 8 + b] * W_sbf2[b * IC + c];
        Ws_pack[idx] = f2bf(v);
    }
    pack_w(W_ji,   HC, HC, Pji,   tid, stride);
    pack_w(W_kj,   HC, HC, Pkj,   tid, stride);
    pack_w(W_down, HC, IC, Pdown, tid, stride);
    pack_w(W_up,   IC, HC, Pup,   tid, stride);
    pack_w(resbW1, HC, HC, Prb1,  tid, stride);
    pack_w(resbW2, HC, HC, Prb2,  tid, stride);
    pack_w(W_lin,  HC, HC, Plin,  tid, stride);
    pack_w(resaW1,             HC, HC, Pra10, tid, stride);
    pack_w(resaW2,             HC, HC, Pra20, tid, stride);
    pack_w(resaW1 + HC * HC,   HC, HC, Pra11, tid, stride);
    pack_w(resaW2 + HC * HC,   HC, HC, Pra21, tid, stride);
}

// ---------------- edge front (MFMA) ----------------
__global__ __launch_bounds__(512) void edge_front_mfma(
    const float* __restrict__ x1, const float* __restrict__ rbf0,
    const unsigned short* __restrict__ Pji, const unsigned short* __restrict__ Pkj,
    const unsigned short* __restrict__ Pdown,
    const float* __restrict__ bji, const float* __restrict__ bkj,
    const float* __restrict__ Wrbf_c,
    float* __restrict__ xji_out, float* __restrict__ xkjd_out) {
    __shared__ __align__(16) unsigned short act[32 * 128];
    __shared__ float rbfs[32][8];
    const int tid = threadIdx.x;
    const int lane = tid & 63;
    const int w = tid >> 6;
    const int e0 = blockIdx.x * 32;

    bf16x8 Bji[4], Bkj[4];
#pragma unroll
    for (int ks = 0; ks < 4; ks++) {
        Bji[ks] = *(const bf16x8*)(Pji + (size_t)((ks * 8 + w) * 64 + lane) * 8);
        Bkj[ks] = *(const bf16x8*)(Pkj + (size_t)((ks * 8 + w) * 64 + lane) * 8);
    }
    const int ntd = w & 3, mtd = w >> 2;
    bf16x8 Bd[4];
#pragma unroll
    for (int ks = 0; ks < 4; ks++)
        Bd[ks] = *(const bf16x8*)(Pdown + (size_t)((ks * 4 + ntd) * 64 + lane) * 8);

    {   // stage x1 tile -> bf16 swizzled LDS
        const float4* s4 = (const float4*)(x1 + (size_t)e0 * HC);
#pragma unroll
        for (int i = tid; i < 1024; i += 512) {
            float4 v = s4[i];
            ldsW8B(act, i >> 5, i & 31, v.x, v.y, v.z, v.w);
        }
        if (tid < 192) rbfs[tid / 6][tid % 6] = rbf0[(size_t)e0 * NRC + tid];
    }
    __syncthreads();

    const int ar = lane & 15;
    const int koff = (lane >> 4) * 8;
    f32x4 aj[2], ak[2];
#pragma unroll
    for (int mt = 0; mt < 2; mt++) {
        f32x4 cj = {0.f, 0.f, 0.f, 0.f};
        f32x4 ck = {0.f, 0.f, 0.f, 0.f};
#pragma unroll
        for (int ks = 0; ks < 4; ks++) {
            bf16x8 a = ldsA(act, mt * 16 + ar, ks * 32 + koff);
            cj = __builtin_amdgcn_mfma_f32_16x16x32_bf16(a, Bji[ks], cj, 0, 0, 0);
            ck = __builtin_amdgcn_mfma_f32_16x16x32_bf16(a, Bkj[ks], ck, 0, 0, 0);
        }
        aj[mt] = cj; ak[mt] = ck;
    }
    __syncthreads();

    const int ch = w * 16 + (lane & 15);
    const int rg = (lane >> 4) * 4;
    {
        float bjv = bji[ch], bkv = bkj[ch];
        float wr[6];
#pragma unroll
        for (int q = 0; q < 6; q++) wr[q] = Wrbf_c[q * HC + ch];
#pragma unroll
        for (int mt = 0; mt < 2; mt++) {
#pragma unroll
            for (int r = 0; r < 4; r++) {
                int m = mt * 16 + rg + r;
                float rv = 0.f;
#pragma unroll
                for (int q = 0; q < 6; q++) rv += rbfs[m][q] * wr[q];
                xji_out[(size_t)(e0 + m) * HC + ch] = selu_f(aj[mt][r] + bjv);
                float xk = selu_f(ak[mt][r] + bkv) * rv;
                ldsW(act, m, ch, f2bf(xk));
            }
        }
    }
    __syncthreads();

    // down-projection 128 -> 64 : wave handles (mtd, ntd)
    f32x4 cd = {0.f, 0.f, 0.f, 0.f};
#pragma unroll
    for (int ks = 0; ks < 4; ks++) {
        bf16x8 a = ldsA(act, mtd * 16 + ar, ks * 32 + koff);
        cd = __builtin_amdgcn_mfma_f32_16x16x32_bf16(a, Bd[ks], cd, 0, 0, 0);
    }
    const int chd = ntd * 16 + (lane & 15);
#pragma unroll
    for (int r = 0; r < 4; r++)
        xkjd_out[(size_t)(e0 + mtd * 16 + rg + r) * IC + chd] = selu_f(cd[r]);
}

// ---------------- triplet (bf16 MFMA) ----------------
__global__ __launch_bounds__(256) void triplet_mfma_kernel(
    const float* __restrict__ sbf, const float* __restrict__ tmat,
    const unsigned short* __restrict__ Wt_pack,
    const unsigned short* __restrict__ Ws_pack,
    const float* __restrict__ xkjd,
    const int* __restrict__ idx_kj, const int* __restrict__ idx_ji,
    float* __restrict__ seg, int nslab) {
    __shared__ __align__(16) unsigned short t_lds[TSLAB][T_LW];
    __shared__ __align__(16) unsigned short s_lds[TSLAB][S_LW];
    __shared__ int kj_s[TSLAB], ji_s[TSLAB];
    const int tid = threadIdx.x;
    const int lane = tid & 63;
    const int w = tid >> 6;

    bf16x8 bt[T_KSTEPS], bs[S_KSTEPS];
#pragma unroll
    for (int s = 0; s < T_KSTEPS; s++)
        bt[s] = *(const bf16x8*)(Wt_pack + (size_t)((s * 4 + w) * 64 + lane) * 8);
#pragma unroll
    for (int s = 0; s < S_KSTEPS; s++)
        bs[s] = *(const bf16x8*)(Ws_pack + (size_t)((s * 4 + w) * 64 + lane) * 8);

    for (int i = tid; i < TSLAB * (T_KSTEPS * 32 - T_K); i += 256) {
        int r = i / (T_KSTEPS * 32 - T_K), c = T_K + i % (T_KSTEPS * 32 - T_K);
        t_lds[r][c] = 0;
    }
    for (int i = tid; i < TSLAB * (S_KSTEPS * 32 - SBF_K); i += 256) {
        int r = i / (S_KSTEPS * 32 - SBF_K), c = SBF_K + i % (S_KSTEPS * 32 - SBF_K);
        s_lds[r][c] = 0;
    }

    for (int slab = blockIdx.x; slab < nslab; slab += gridDim.x) {
        const size_t t0 = (size_t)slab * TSLAB;
        {
            const float4* st = (const float4*)(tmat + t0 * T_K);
            for (int i = tid; i < TSLAB * T_K / 4; i += 256) {
                float4 v = st[i];
                int e = 4 * i;
                int r = e / T_K, c = e - r * T_K;
                float vv[4] = {v.x, v.y, v.z, v.w};
#pragma unroll
                for (int q = 0; q < 4; q++) {
                    t_lds[r][c] = f2bf(vv[q]);
                    if (++c == T_K) { c = 0; ++r; }
                }
            }
            const float4* ss = (const float4*)(sbf + t0 * SBF_K);
            for (int i = tid; i < TSLAB * SBF_K / 4; i += 256) {
                float4 v = ss[i];
                int e = 4 * i;
                int r = e / SBF_K, c = e - r * SBF_K;
                float vv[4] = {v.x, v.y, v.z, v.w};
#pragma unroll
                for (int q = 0; q < 4; q++) {
                    s_lds[r][c] = f2bf(vv[q]);
                    if (++c == SBF_K) { c = 0; ++r; }
                }
            }
            if (tid < TSLAB) {
                kj_s[tid] = idx_kj[t0 + tid];
                ji_s[tid] = idx_ji[t0 + tid];
            }
        }
        __syncthreads();

        const int arow0 = lane & 15;
        const int koff = (lane >> 4) * 8;
        f32x4 acc_t[2], acc_s[2];
#pragma unroll
        for (int mt = 0; mt < 2; mt++) {
            acc_t[mt] = (f32x4){0.f, 0.f, 0.f, 0.f};
            acc_s[mt] = (f32x4){0.f, 0.f, 0.f, 0.f};
        }
#pragma unroll
        for (int mt = 0; mt < 2; mt++) {
            const int row = mt * 16 + arow0;
#pragma unroll
            for (int s = 0; s < T_KSTEPS; s++) {
                bf16x8 a = *(const bf16x8*)&t_lds[row][s * 32 + koff];
                acc_t[mt] = __builtin_amdgcn_mfma_f32_16x16x32_bf16(a, bt[s], acc_t[mt], 0, 0, 0);
            }
#pragma unroll
            for (int s = 0; s < S_KSTEPS; s++) {
                bf16x8 a = *(const bf16x8*)&s_lds[row][s * 32 + koff];
                acc_s[mt] = __builtin_amdgcn_mfma_f32_16x16x32_bf16(a, bs[s], acc_s[mt], 0, 0, 0);
            }
        }

        const int ch = w * 16 + (lane & 15);
#pragma unroll
        for (int mt = 0; mt < 2; mt++) {
#pragma unroll
            for (int r = 0; r < 4; r++) {
                int ml = mt * 16 + (lane >> 4) * 4 + r;
                int ekj = kj_s[ml];
                int eji = ji_s[ml];
                float y = xkjd[(size_t)ekj * IC + ch] * acc_s[mt][r] * acc_t[mt][r];
                atomicAdd(&seg[(size_t)eji * IC + ch], y);
            }
        }
        __syncthreads();
    }
}

// ---------------- edge back (MFMA, chained GEMMs, skips in C-layout regs) ----------------
__global__ __launch_bounds__(512) void edge_back_mfma(
    const float* __restrict__ seg, const float* __restrict__ xji,
    const float* __restrict__ x1, const float* __restrict__ rbf0,
    const unsigned short* __restrict__ Pup,
    const unsigned short* __restrict__ Prb1, const unsigned short* __restrict__ Prb2,
    const unsigned short* __restrict__ Plin,
    const unsigned short* __restrict__ Pra10, const unsigned short* __restrict__ Pra20,
    const unsigned short* __restrict__ Pra11, const unsigned short* __restrict__ Pra21,
    const float* __restrict__ bb1, const float* __restrict__ bb2,
    const float* __restrict__ blin,
    const float* __restrict__ ba1, const float* __restrict__ ba2,
    const float* __restrict__ Wrbf,
    float* __restrict__ e1_out, float* __restrict__ e2_out) {
    __shared__ __align__(16) unsigned short act[32 * 128];
    __shared__ float rbfs[32][8];
    const int tid = threadIdx.x;
    const int lane = tid & 63;
    const int w = tid >> 6;
    const int e0 = blockIdx.x * 32;
    const int ch = w * 16 + (lane & 15);
    const int rg = (lane >> 4) * 4;

    bf16x8 Bup[2], B1[4], B2[4], BL[4];
#pragma unroll
    for (int ks = 0; ks < 2; ks++)
        Bup[ks] = *(const bf16x8*)(Pup + (size_t)((ks * 8 + w) * 64 + lane) * 8);
#pragma unroll
    for (int ks = 0; ks < 4; ks++) {
        B1[ks] = *(const bf16x8*)(Prb1 + (size_t)((ks * 8 + w) * 64 + lane) * 8);
        B2[ks] = *(const bf16x8*)(Prb2 + (size_t)((ks * 8 + w) * 64 + lane) * 8);
        BL[ks] = *(const bf16x8*)(Plin + (size_t)((ks * 8 + w) * 64 + lane) * 8);
    }

    {   // stage seg tile (32x64 f32) -> bf16 swizzled LDS (cols 0..63)
        const float4* s4 = (const float4*)(seg + (size_t)e0 * IC);
        float4 v = s4[tid];
        ldsW8B(act, tid >> 4, tid & 15, v.x, v.y, v.z, v.w);
        if (tid < 192) rbfs[tid / 6][tid % 6] = rbf0[(size_t)e0 * NRC + tid];
    }
    float skip[2][4], x1v[2][4];
#pragma unroll
    for (int mt = 0; mt < 2; mt++)
#pragma unroll
        for (int r = 0; r < 4; r++) {
            skip[mt][r] = xji[(size_t)(e0 + mt * 16 + rg + r) * HC + ch];
            x1v[mt][r]  = x1 [(size_t)(e0 + mt * 16 + rg + r) * HC + ch];
        }
    __syncthreads();

    f32x4 acc[2];
    float h[2][4];

    // ---- up: h = selu(seg@Wup) + xji ----
    mm2<2>(act, Bup, lane, acc);
    __syncthreads();
#pragma unroll
    for (int mt = 0; mt < 2; mt++)
#pragma unroll
        for (int r = 0; r < 4; r++) {
            h[mt][r] = selu_f(acc[mt][r]) + skip[mt][r];
            ldsW(act, mt * 16 + rg + r, ch, f2bf(h[mt][r]));
            skip[mt][r] = h[mt][r];
        }
    __syncthreads();

    // ---- res-before: t = selu(h@W1+b1) ----
    mm2<4>(act, B1, lane, acc);
    __syncthreads();
    {
        float bv = bb1[ch];
#pragma unroll
        for (int mt = 0; mt < 2; mt++)
#pragma unroll
            for (int r = 0; r < 4; r++)
                ldsW(act, mt * 16 + rg + r, ch, f2bf(selu_f(acc[mt][r] + bv)));
    }
    __syncthreads();
    // h += selu(t@W2+b2)
    mm2<4>(act, B2, lane, acc);
    __syncthreads();
    bf16x8 Ba1[4], Ba2[4];
#pragma unroll
    for (int ks = 0; ks < 4; ks++) {
        Ba1[ks] = *(const bf16x8*)(Pra10 + (size_t)((ks * 8 + w) * 64 + lane) * 8);
        Ba2[ks] = *(const bf16x8*)(Pra20 + (size_t)((ks * 8 + w) * 64 + lane) * 8);
    }
    {
        float bv = bb2[ch];
#pragma unroll
        for (int mt = 0; mt < 2; mt++)
#pragma unroll
            for (int r = 0; r < 4; r++) {
                h[mt][r] = skip[mt][r] + selu_f(acc[mt][r] + bv);
                ldsW(act, mt * 16 + rg + r, ch, f2bf(h[mt][r]));
            }
    }
    __syncthreads();

    // ---- lin: h = selu(h@Wlin+blin) + x1 ----
    mm2<4>(act, BL, lane, acc);
    __syncthreads();
    {
        float bv = blin[ch];
#pragma unroll
        for (int mt = 0; mt < 2; mt++)
#pragma unroll
            for (int r = 0; r < 4; r++) {
                h[mt][r] = selu_f(acc[mt][r] + bv) + x1v[mt][r];
                ldsW(act, mt * 16 + rg + r, ch, f2bf(h[mt][r]));
                skip[mt][r] = h[mt][r];
            }
    }
    __syncthreads();

    // ---- res-after x2 ----
#pragma unroll
    for (int rb = 0; rb < 2; rb++) {
        mm2<4>(act, Ba1, lane, acc);
        __syncthreads();
        {
            float bv = ba1[rb * HC + ch];
#pragma unroll
            for (int mt = 0; mt < 2; mt++)
#pragma unroll
                for (int r = 0; r < 4; r++)
                    ldsW(act, mt * 16 + rg + r, ch, f2bf(selu_f(acc[mt][r] + bv)));
        }
        __syncthreads();
        mm2<4>(act, Ba2, lane, acc);
        __syncthreads();
        if (rb == 0) {
#pragma unroll
            for (int ks = 0; ks < 4; ks++) {
                Ba1[ks] = *(const bf16x8*)(Pra11 + (size_t)((ks * 8 + w) * 64 + lane) * 8);
                Ba2[ks] = *(const bf16x8*)(Pra21 + (size_t)((ks * 8 + w) * 64 + lane) * 8);
            }
        }
        {
            float bv = ba2[rb * HC + ch];
#pragma unroll
            for (int mt = 0; mt < 2; mt++)
#pragma unroll
                for (int r = 0; r < 4; r++) {
                    h[mt][r] = skip[mt][r] + selu_f(acc[mt][r] + bv);
                    skip[mt][r] = h[mt][r];
                }
        }
        if (rb == 0) {
#pragma unroll
            for (int mt = 0; mt < 2; mt++)
#pragma unroll
                for (int r = 0; r < 4; r++)
                    ldsW(act, mt * 16 + rg + r, ch, f2bf(h[mt][r]));
            __syncthreads();
        }
    }

    // ---- epilogue: e1 = h ; e2 = (rbf0@Wrbf)*h ----
    {
        float wr[6];
#pragma unroll
        for (int q = 0; q < 6; q++) wr[q] = Wrbf[q * HC + ch];
#pragma unroll
        for (int mt = 0; mt < 2; mt++)
#pragma unroll
            for (int r = 0; r < 4; r++) {
                int m = mt * 16 + rg + r;
                float rv = 0.f;
#pragma unroll
                for (int q = 0; q < 6; q++) rv += rbfs[m][q] * wr[q];
                size_t e = (size_t)(e0 + m);
                e1_out[e * HC + ch] = h[mt][r];
                e2_out[e * HC + ch] = rv * h[mt][r];
            }
    }
}

extern "C" void kernel_launch(void* const* d_in, const int* in_sizes, int n_in,
                              void* d_out, int out_size, void* d_ws, size_t ws_size,
                              hipStream_t stream) {
    const float* x1     = (const float*)d_in[0];
    const float* rbf0   = (const float*)d_in[1];
    const float* sbf    = (const float*)d_in[2];
    const float* tmat   = (const float*)d_in[3];
    const float* W_rbf1 = (const float*)d_in[5];
    const float* W_rbf2 = (const float*)d_in[6];
    const float* W_sbf1 = (const float*)d_in[7];
    const float* W_sbf2 = (const float*)d_in[8];
    const float* W_t1   = (const float*)d_in[9];
    const float* W_t2   = (const float*)d_in[10];
    const float* W_rbf  = (const float*)d_in[11];
    const float* W_kj   = (const float*)d_in[12];
    const float* b_kj   = (const float*)d_in[13];
    const float* W_ji   = (const float*)d_in[14];
    const float* b_ji   = (const float*)d_in[15];
    const float* W_down = (const float*)d_in[16];
    const float* W_up   = (const float*)d_in[17];
    const float* W_lin  = (const float*)d_in[18];
    const float* b_lin  = (const float*)d_in[19];
    const float* resbW1 = (const float*)d_in[20];
    const float* resbb1 = (const float*)d_in[21];
    const float* resbW2 = (const float*)d_in[22];
    const float* resbb2 = (const float*)d_in[23];
    const float* resaW1 = (const float*)d_in[24];
    const float* resab1 = (const float*)d_in[25];
    const float* resaW2 = (const float*)d_in[26];
    const float* resab2 = (const float*)d_in[27];
    const int* idx_kj   = (const int*)d_in[28];
    const int* idx_ji   = (const int*)d_in[29];

    float* ws = (float*)d_ws;
    float* Wrbf_c = ws;                                    // 768 f32
    unsigned short* u0 = (unsigned short*)(ws + 768);
    unsigned short* Wt_pack = u0;            // 20480
    unsigned short* Ws_pack = Wt_pack + 20480; // 4096
    unsigned short* Pji   = Ws_pack + 4096;  // 16384
    unsigned short* Pkj   = Pji + 16384;
    unsigned short* Pdown = Pkj + 16384;     // 8192
    unsigned short* Pup   = Pdown + 8192;    // 8192
    unsigned short* Prb1  = Pup + 8192;      // 16384
    unsigned short* Prb2  = Prb1 + 16384;
    unsigned short* Plin  = Prb2 + 16384;
    unsigned short* Pra10 = Plin + 16384;
    unsigned short* Pra20 = Pra10 + 16384;
    unsigned short* Pra11 = Pra20 + 16384;
    unsigned short* Pra21 = Pra11 + 16384;
    // total ushorts = 188416 = 94208 f32 words
    float* xkjd = ws + 768 + 94208;
    float* seg  = xkjd + (size_t)EDGES * IC;

    float* e1_out = (float*)d_out;
    float* e2_out = e1_out + (size_t)EDGES * HC;
    float* xji    = e1_out;  // park x_ji in the e1 output region

    hipMemsetAsync(seg, 0, (size_t)EDGES * IC * sizeof(float), stream);
    combos_kernel<<<64, 256, 0, stream>>>(W_rbf1, W_rbf2, W_sbf1, W_sbf2, W_t1, W_t2,
                                          W_ji, W_kj, W_down, W_up, resbW1, resbW2,
                                          W_lin, resaW1, resaW2,
                                          Wrbf_c, Wt_pack, Ws_pack,
                                          Pji, Pkj, Pdown, Pup, Prb1, Prb2, Plin,
                                          Pra10, Pra20, Pra11, Pra21);
    edge_front_mfma<<<EDGES / 32, 512, 0, stream>>>(x1, rbf0, Pji, Pkj, Pdown,
                                                    b_ji, b_kj, Wrbf_c, xji, xkjd);
    triplet_mfma_kernel<<<2048, 256, 0, stream>>>(sbf, tmat, Wt_pack, Ws_pack, xkjd,
                                                  idx_kj, idx_ji, seg, TRIPS / TSLAB);
    edge_back_mfma<<<EDGES / 32, 512, 0, stream>>>(seg, xji, x1, rbf0,
                                                   Pup, Prb1, Prb2, Plin,
                                                   Pra10, Pra20, Pra11, Pra21,
                                                   resbb1, resbb2, b_lin,
                                                   resab1, resab2, W_rbf,
                                                   e1_out, e2_out);
}